// Round 1
// baseline (3130.829 us; speedup 1.0000x reference)
//
#include <hip/hip_runtime.h>
#include <hip/hip_bf16.h>
#include <math.h>

// Problem constants
#define B_   128
#define NQ_  256
#define NC_  128
#define D_   1024
#define AD_  256   // attn_dim
#define MH_  512   // matrix_w hidden (2*attn_dim)
#define SH_  128   // smooth_w hidden (attn_dim/2)

// GEMM tile config: 64x64 tile, BK=16, 256 threads, 4x4 micro-tile
#define BM 64
#define BN 64
#define BK 16

enum { A_PLAIN = 0, A_SQDIFF = 1 };
enum { EPI_STORE = 0, EPI_BIAS = 1, EPI_TANH_BIAS = 2, EPI_MATRIX = 3 };

// ---------------------------------------------------------------------------
// Generic batched NN GEMM: C[b] = epi( A[b] (MxK, row-major) @ B (KxN, row-major) )
// A optionally transformed as (A0-A1)^2 elementwise (for (query-wc)^2).
// B batched via strideB (0 for shared weights).
// ---------------------------------------------------------------------------
template<int AMODE, int EPI>
__global__ __launch_bounds__(256)
void gemm_nn_kernel(const float* __restrict__ A0, const float* __restrict__ A1,
                    const float* __restrict__ Bw, size_t strideB,
                    const float* __restrict__ bias,
                    float* __restrict__ Cout, const float* __restrict__ Prev,
                    int M, int N, int K)
{
    const int b = blockIdx.z;
    const float* Ab0 = A0 + (size_t)b * M * K;
    const float* Ab1 = (AMODE == A_SQDIFF) ? (A1 + (size_t)b * M * K) : nullptr;
    const float* Bb  = Bw + (size_t)b * strideB;
    float* Cb = Cout + (size_t)b * M * N;

    __shared__ float As[BK][BM + 4];   // [k][m]
    __shared__ float Bs[BK][BN + 4];   // [k][n]

    const int tid = threadIdx.x;
    const int tx = tid & 15;
    const int ty = tid >> 4;
    const int m0 = blockIdx.y * BM;
    const int n0 = blockIdx.x * BN;

    const int arow = tid >> 2;          // 0..63
    const int acol = (tid & 3) << 2;    // 0,4,8,12
    const int brow = tid >> 4;          // 0..15
    const int bcol = (tid & 15) << 2;   // 0..60

    float acc[4][4] = {};

    for (int k0 = 0; k0 < K; k0 += BK) {
        float4 av = *(const float4*)(Ab0 + (size_t)(m0 + arow) * K + k0 + acol);
        if (AMODE == A_SQDIFF) {
            float4 wv = *(const float4*)(Ab1 + (size_t)(m0 + arow) * K + k0 + acol);
            av.x -= wv.x; av.y -= wv.y; av.z -= wv.z; av.w -= wv.w;
            av.x *= av.x; av.y *= av.y; av.z *= av.z; av.w *= av.w;
        }
        As[acol + 0][arow] = av.x;
        As[acol + 1][arow] = av.y;
        As[acol + 2][arow] = av.z;
        As[acol + 3][arow] = av.w;
        *(float4*)&Bs[brow][bcol] =
            *(const float4*)(Bb + (size_t)(k0 + brow) * N + n0 + bcol);
        __syncthreads();
        #pragma unroll
        for (int k = 0; k < BK; ++k) {
            float a[4], bb[4];
            *(float4*)a  = *(const float4*)&As[k][ty << 2];
            *(float4*)bb = *(const float4*)&Bs[k][tx << 2];
            #pragma unroll
            for (int i = 0; i < 4; ++i)
                #pragma unroll
                for (int j = 0; j < 4; ++j)
                    acc[i][j] += a[i] * bb[j];
        }
        __syncthreads();
    }

    #pragma unroll
    for (int i = 0; i < 4; ++i) {
        const int m = m0 + (ty << 2) + i;
        #pragma unroll
        for (int j = 0; j < 4; ++j) {
            const int n = n0 + (tx << 2) + j;
            float v = acc[i][j];
            if (EPI == EPI_BIAS) {
                v += bias[n];
            } else if (EPI == EPI_TANH_BIAS) {
                v = tanhf(v + bias[n]);
            } else if (EPI == EPI_MATRIX) {
                const float p = Prev ? Prev[(size_t)b * M * N + (size_t)m * N + n] : 1.0f;
                v = tanhf(v + bias[n]) + p;
                v = fminf(fmaxf(v, -1.0f), 1.0f);
            }
            Cb[(size_t)m * N + n] = v;
        }
    }
}

// ---------------------------------------------------------------------------
// Scores: S[b,c,q] = leakyrelu_0.1( sum_d C[b,c,d] * (Q[b,q,d] * M[b,q,d]) )
// A@B^T form: both operands contract their fast axis.
// ---------------------------------------------------------------------------
template<bool HASM>
__global__ __launch_bounds__(256)
void scores_kernel(const float* __restrict__ Ctx, const float* __restrict__ Q,
                   const float* __restrict__ Mtx, float* __restrict__ S)
{
    const int b = blockIdx.z;
    const float* Cb = Ctx + (size_t)b * NC_ * D_;
    const float* Qb = Q   + (size_t)b * NQ_ * D_;
    const float* Mb = HASM ? (Mtx + (size_t)b * NQ_ * D_) : nullptr;

    __shared__ float As[BK][BM + 4];   // [k][c]
    __shared__ float Bs[BK][BN + 4];   // [k][q]

    const int tid = threadIdx.x;
    const int tx = tid & 15;
    const int ty = tid >> 4;
    const int m0 = blockIdx.y * BM;   // c tile
    const int n0 = blockIdx.x * BN;   // q tile
    const int arow = tid >> 2;        // 0..63
    const int acol = (tid & 3) << 2;  // 0,4,8,12

    float acc[4][4] = {};

    for (int k0 = 0; k0 < D_; k0 += BK) {
        float4 av = *(const float4*)(Cb + (size_t)(m0 + arow) * D_ + k0 + acol);
        As[acol + 0][arow] = av.x;
        As[acol + 1][arow] = av.y;
        As[acol + 2][arow] = av.z;
        As[acol + 3][arow] = av.w;
        float4 qv = *(const float4*)(Qb + (size_t)(n0 + arow) * D_ + k0 + acol);
        if (HASM) {
            float4 mv = *(const float4*)(Mb + (size_t)(n0 + arow) * D_ + k0 + acol);
            qv.x *= mv.x; qv.y *= mv.y; qv.z *= mv.z; qv.w *= mv.w;
        }
        Bs[acol + 0][arow] = qv.x;
        Bs[acol + 1][arow] = qv.y;
        Bs[acol + 2][arow] = qv.z;
        Bs[acol + 3][arow] = qv.w;
        __syncthreads();
        #pragma unroll
        for (int k = 0; k < BK; ++k) {
            float a[4], bb[4];
            *(float4*)a  = *(const float4*)&As[k][ty << 2];
            *(float4*)bb = *(const float4*)&Bs[k][tx << 2];
            #pragma unroll
            for (int i = 0; i < 4; ++i)
                #pragma unroll
                for (int j = 0; j < 4; ++j)
                    acc[i][j] += a[i] * bb[j];
        }
        __syncthreads();
    }

    #pragma unroll
    for (int i = 0; i < 4; ++i) {
        const int c = m0 + (ty << 2) + i;
        #pragma unroll
        for (int j = 0; j < 4; ++j) {
            const int q = n0 + (tx << 2) + j;
            float v = acc[i][j];
            v = (v >= 0.0f) ? v : 0.1f * v;   // LeakyReLU(0.1)
            S[(size_t)b * NC_ * NQ_ + (size_t)c * NQ_ + q] = v;
        }
    }
}

// One wave per (b,c): inverse l2 norm over q (256 elems) of leaky'd scores.
__global__ void cnorm_kernel(const float* __restrict__ S, float* __restrict__ cn)
{
    const int w = (blockIdx.x * blockDim.x + threadIdx.x) >> 6;
    const int lane = threadIdx.x & 63;
    if (w >= B_ * NC_) return;
    const float* row = S + (size_t)w * NQ_;
    float4 v = *(const float4*)&row[lane * 4];
    float s = v.x * v.x + v.y * v.y + v.z * v.z + v.w * v.w;
    #pragma unroll
    for (int off = 32; off; off >>= 1) s += __shfl_xor(s, off, 64);
    if (lane == 0) cn[w] = 1.0f / (sqrtf(s) + 1e-8f);
}

// One wave per (b,q): softmax over c of S[b,c,q]*cninv[b,c]*smooth[b,q].
__global__ void softmax_kernel(const float* __restrict__ S, const float* __restrict__ cn,
                               const float* __restrict__ smooth, float* __restrict__ attn)
{
    const int w = (blockIdx.x * blockDim.x + threadIdx.x) >> 6;  // b*NQ_+q
    const int lane = threadIdx.x & 63;
    if (w >= B_ * NQ_) return;
    const int b = w >> 8;
    const int q = w & (NQ_ - 1);
    const float sm = smooth ? smooth[w] : 10.0f;
    const float* Sb  = S  + (size_t)b * NC_ * NQ_;
    const float* cnb = cn + (size_t)b * NC_;
    float v0 = Sb[(size_t)lane * NQ_ + q]        * cnb[lane]      * sm;
    float v1 = Sb[(size_t)(lane + 64) * NQ_ + q] * cnb[lane + 64] * sm;
    float m = fmaxf(v0, v1);
    #pragma unroll
    for (int off = 32; off; off >>= 1) m = fmaxf(m, __shfl_xor(m, off, 64));
    const float e0 = expf(v0 - m);
    const float e1 = expf(v1 - m);
    float s = e0 + e1;
    #pragma unroll
    for (int off = 32; off; off >>= 1) s += __shfl_xor(s, off, 64);
    const float inv = 1.0f / s;
    float* o = attn + (size_t)w * NC_;
    o[lane]      = e0 * inv;
    o[lane + 64] = e1 * inv;
}

// One wave per (b,q): in-place l2norm of a 256-elem row.
__global__ void rownorm_kernel(float* __restrict__ X)
{
    const int w = (blockIdx.x * blockDim.x + threadIdx.x) >> 6;
    const int lane = threadIdx.x & 63;
    if (w >= B_ * NQ_) return;
    float* row = X + (size_t)w * AD_;
    float4 v = *(float4*)&row[lane * 4];
    float s = v.x * v.x + v.y * v.y + v.z * v.z + v.w * v.w;
    #pragma unroll
    for (int off = 32; off; off >>= 1) s += __shfl_xor(s, off, 64);
    const float inv = 1.0f / (sqrtf(s) + 1e-8f);
    v.x *= inv; v.y *= inv; v.z *= inv; v.w *= inv;
    *(float4*)&row[lane * 4] = v;
}

// One wave per (b,q): smooth = relu(h2 . sw_W2 + sw_b2 + smooth_prev)
__global__ void smooth_kernel(const float* __restrict__ h2, const float* __restrict__ W2,
                              const float* __restrict__ b2, float* __restrict__ smooth,
                              int first)
{
    const int w = (blockIdx.x * blockDim.x + threadIdx.x) >> 6;
    const int lane = threadIdx.x & 63;
    if (w >= B_ * NQ_) return;
    const float* r = h2 + (size_t)w * SH_;
    float s = r[lane] * W2[lane] + r[lane + 64] * W2[lane + 64];
    #pragma unroll
    for (int off = 32; off; off >>= 1) s += __shfl_xor(s, off, 64);
    if (lane == 0) {
        const float sp = first ? 10.0f : smooth[w];
        smooth[w] = fmaxf(s + b2[0] + sp, 0.0f);
    }
}

__global__ void copy4_kernel(const float4* __restrict__ src, float4* __restrict__ dst, int n)
{
    int i = blockIdx.x * blockDim.x + threadIdx.x;
    const int stride = gridDim.x * blockDim.x;
    for (; i < n; i += stride) dst[i] = src[i];
}

// ---------------------------------------------------------------------------
extern "C" void kernel_launch(void* const* d_in, const int* in_sizes, int n_in,
                              void* d_out, int out_size, void* d_ws, size_t ws_size,
                              hipStream_t stream)
{
    (void)in_sizes; (void)n_in; (void)out_size; (void)ws_size;

    const float* query   = (const float*)d_in[0];
    const float* context = (const float*)d_in[1];
    const float* cw_W    = (const float*)d_in[2];
    const float* cw_b    = (const float*)d_in[3];
    const float* sw_W1   = (const float*)d_in[4];
    const float* sw_b1   = (const float*)d_in[5];
    const float* sw_W2   = (const float*)d_in[6];
    const float* sw_b2   = (const float*)d_in[7];
    const float* mw_W1   = (const float*)d_in[8];
    const float* mw_b1   = (const float*)d_in[9];
    const float* mw_W2   = (const float*)d_in[10];
    const float* mw_b2   = (const float*)d_in[11];

    float* out      = (float*)d_out;
    float* out_q    = out;                                  // (B,NQ,D)
    float* out_wc   = out + (size_t)B_ * NQ_ * D_;          // (B,NQ,D)
    float* out_attn = out_wc + (size_t)B_ * NQ_ * D_;       // (B,NQ,NC)

    // matrix state lives in the out_query region until the final copy.
    float* matrix = out_q;

    // workspace layout (floats): needs ~117.7 MB
    float* ws     = (float*)d_ws;
    float* S      = ws;                                     // (B,NC,NQ) 4.19M
    float* smooth = S + (size_t)B_ * NC_ * NQ_;             // (B,NQ)    32K
    float* cnorm  = smooth + B_ * NQ_;                      // (B,NC)    16K
    float* common = cnorm + B_ * NC_;                       // (B,NQ,AD) 8.39M
    float* h      = common + (size_t)B_ * NQ_ * AD_;        // (B,NQ,MH) 16.78M
    float* h2     = S;                                      // overlay: scans vs layers

    const dim3 blk(256);
    const int wave_blocks_bq = (B_ * NQ_ * 64) / 256;   // 8192
    const int wave_blocks_bc = (B_ * NC_ * 64) / 256;   // 4096

    // ---- scan helper (inline sequence) ----
    auto scan = [&](const float* mtx, const float* smo) {
        if (mtx)
            scores_kernel<true><<<dim3(NQ_ / BN, NC_ / BM, B_), blk, 0, stream>>>(
                context, query, mtx, S);
        else
            scores_kernel<false><<<dim3(NQ_ / BN, NC_ / BM, B_), blk, 0, stream>>>(
                context, query, nullptr, S);
        cnorm_kernel<<<wave_blocks_bc, blk, 0, stream>>>(S, cnorm);
        softmax_kernel<<<wave_blocks_bq, blk, 0, stream>>>(S, cnorm, smo, out_attn);
        // wc = attn @ context : M=NQ, N=D, K=NC, B batched on both sides
        gemm_nn_kernel<A_PLAIN, EPI_STORE><<<dim3(D_ / BN, NQ_ / BM, B_), blk, 0, stream>>>(
            out_attn, nullptr, context, (size_t)NC_ * D_, nullptr, out_wc, nullptr,
            NQ_, D_, NC_);
    };

    auto layer = [&](int i) {
        // common_raw = (query - wc)^2 @ cw_W[i] + cw_b[i]
        gemm_nn_kernel<A_SQDIFF, EPI_BIAS><<<dim3(AD_ / BN, NQ_ / BM, B_), blk, 0, stream>>>(
            query, out_wc, cw_W + (size_t)i * D_ * AD_, 0, cw_b + (size_t)i * AD_,
            common, nullptr, NQ_, AD_, D_);
        rownorm_kernel<<<wave_blocks_bq, blk, 0, stream>>>(common);
        // h = tanh(common @ mw_W1 + b1)
        gemm_nn_kernel<A_PLAIN, EPI_TANH_BIAS><<<dim3(MH_ / BN, NQ_ / BM, B_), blk, 0, stream>>>(
            common, nullptr, mw_W1 + (size_t)i * AD_ * MH_, 0, mw_b1 + (size_t)i * MH_,
            h, nullptr, NQ_, MH_, AD_);
        // matrix = clip(tanh(h @ mw_W2 + b2) + matrix_prev, -1, 1)
        gemm_nn_kernel<A_PLAIN, EPI_MATRIX><<<dim3(D_ / BN, NQ_ / BM, B_), blk, 0, stream>>>(
            h, nullptr, mw_W2 + (size_t)i * MH_ * D_, 0, mw_b2 + (size_t)i * D_,
            matrix, (i == 0 ? nullptr : matrix), NQ_, D_, MH_);
        // h2 = tanh(common @ sw_W1 + b1)
        gemm_nn_kernel<A_PLAIN, EPI_TANH_BIAS><<<dim3(SH_ / BN, NQ_ / BM, B_), blk, 0, stream>>>(
            common, nullptr, sw_W1 + (size_t)i * AD_ * SH_, 0, sw_b1 + (size_t)i * SH_,
            h2, nullptr, NQ_, SH_, AD_);
        // smooth = relu(h2 @ sw_W2 + b2 + smooth_prev)
        smooth_kernel<<<wave_blocks_bq, blk, 0, stream>>>(
            h2, sw_W2 + (size_t)i * SH_, sw_b2 + i, smooth, (i == 0) ? 1 : 0);
    };

    scan(nullptr, nullptr);   // matrix = 1, smooth = 10
    layer(0);
    scan(matrix, smooth);
    layer(1);
    scan(matrix, smooth);     // final wc -> out_wc, final attn -> out_attn

    // finally, overwrite the matrix scratch region with the query passthrough
    copy4_kernel<<<4096, blk, 0, stream>>>(
        (const float4*)query, (float4*)out_q, (int)((size_t)B_ * NQ_ * D_ / 4));
}

// Round 3
// 1442.647 us; speedup vs baseline: 2.1702x; 2.1702x over previous
//
#include <hip/hip_runtime.h>
#include <hip/hip_bf16.h>
#include <math.h>

// Problem constants
#define B_   128
#define NQ_  256
#define NC_  128
#define D_   1024
#define AD_  256   // attn_dim
#define MH_  512   // matrix hidden (2*attn_dim)
#define SH_  128   // smooth hidden (attn_dim/2)

typedef unsigned short u16;
typedef __attribute__((ext_vector_type(8))) short short8;   // 8 bf16 = 4 VGPRs
typedef __attribute__((ext_vector_type(4))) float f32x4;

__device__ __forceinline__ u16 f2b(float x) {
    __hip_bfloat16 h = __float2bfloat16(x);
    return *reinterpret_cast<u16*>(&h);
}
__device__ __forceinline__ float b2f(u16 u) {
    __hip_bfloat16 h = *reinterpret_cast<__hip_bfloat16*>(&u);
    return __bfloat162float(h);
}

// global -> LDS direct (16B/lane). LDS dest = wave-uniform base + lane*16.
#define GLOAD16(gp, lp)                                                        \
    __builtin_amdgcn_global_load_lds(                                          \
        (const __attribute__((address_space(1))) unsigned int*)(gp),           \
        (__attribute__((address_space(3))) unsigned int*)(lp), 16, 0, 0)

// ---------------------------------------------------------------------------
// MFMA GEMM: C[b](MxN) = epi( A[b](MxK, K-fast bf16) @ B[b](NxK, K-fast bf16)^T )
// 128x128 tile, BK=64, 256 threads = 4 waves (2x2), 64x64 per wave.
// LDS layout [row][64] bf16 (128B rows), XOR-swizzled: byte ^= (row&7)<<4.
// Staged via global_load_lds with pre-swizzled per-lane SOURCE (linear dest).
// ---------------------------------------------------------------------------
enum { EPI_SCORES = 0, EPI_WC_SQD = 1, EPI_WC_OUT = 2,
       EPI_COMMON = 3, EPI_TANH = 4, EPI_MATRIX = 5 };

template<int EPI>
__global__ __launch_bounds__(256)
void mm_bt(const u16* __restrict__ A, long sA,
           const u16* __restrict__ Bw, long sB,
           const float* __restrict__ bias,
           float* Cf, u16* Cb,
           const float* __restrict__ Qf, const float* Prev,
           int M, int N, int K)
{
    __shared__ u16 As[128 * 64];
    __shared__ u16 Bs[128 * 64];

    const int b  = blockIdx.z;
    const int m0 = blockIdx.y * 128;
    const int n0 = blockIdx.x * 128;
    const u16* Ab = A + (size_t)b * sA + (size_t)m0 * K;
    const u16* Bb = Bw + (size_t)b * sB + (size_t)n0 * K;

    const int tid = threadIdx.x;
    const int w = tid >> 6, l = tid & 63;
    const int wm = w >> 1, wn = w & 1;

    // staging: 32 insts/block (16 A + 16 B), 8 per wave; inst covers 8 rows.
    const int  rsel = l >> 3;                  // 0..7  row within inst
    const int  csel = ((l & 7) ^ rsel) * 8;    // pre-swizzled source col (elems)
    const bool isA = (w < 2);
    const u16* Gb = isA ? Ab : Bb;
    u16* Ls = isA ? As : Bs;
    const int instbase = (isA ? w : (w - 2)) * 8;

    f32x4 acc[4][4] = {};

    for (int k0 = 0; k0 < K; k0 += 64) {
        #pragma unroll
        for (int j = 0; j < 8; ++j) {
            const int row = (instbase + j) * 8 + rsel;
            GLOAD16(Gb + (size_t)row * K + k0 + csel, Ls + (instbase + j) * 512);
        }
        __syncthreads();
        #pragma unroll
        for (int ks = 0; ks < 2; ++ks) {
            short8 af[4], bf[4];
            #pragma unroll
            for (int mi = 0; mi < 4; ++mi) {
                const int row = wm * 64 + mi * 16 + (l & 15);
                const int off = (row * 128 + ks * 64 + (l >> 4) * 16) ^ ((row & 7) << 4);
                af[mi] = *(const short8*)((const char*)As + off);
            }
            #pragma unroll
            for (int ni = 0; ni < 4; ++ni) {
                const int row = wn * 64 + ni * 16 + (l & 15);
                const int off = (row * 128 + ks * 64 + (l >> 4) * 16) ^ ((row & 7) << 4);
                bf[ni] = *(const short8*)((const char*)Bs + off);
            }
            #pragma unroll
            for (int mi = 0; mi < 4; ++mi)
                #pragma unroll
                for (int ni = 0; ni < 4; ++ni)
                    acc[mi][ni] = __builtin_amdgcn_mfma_f32_16x16x32_bf16(
                        af[mi], bf[ni], acc[mi][ni], 0, 0, 0);
        }
        __syncthreads();
    }

    // epilogue: D frag mapping col = lane&15, row = (lane>>4)*4 + reg  [m89]
    const size_t cb0 = (size_t)b * M * N;
    #pragma unroll
    for (int mi = 0; mi < 4; ++mi) {
        #pragma unroll
        for (int r = 0; r < 4; ++r) {
            const int m = m0 + wm * 64 + mi * 16 + ((l >> 4) << 2) + r;
            const size_t rowoff = cb0 + (size_t)m * N;
            #pragma unroll
            for (int ni = 0; ni < 4; ++ni) {
                const int n = n0 + wn * 64 + ni * 16 + (l & 15);
                float v = acc[mi][ni][r];
                if (EPI == EPI_SCORES) {
                    v = (v >= 0.0f) ? v : 0.1f * v;       // LeakyReLU(0.1)
                    Cf[rowoff + n] = v;
                } else if (EPI == EPI_WC_SQD) {
                    const float d = Qf[rowoff + n] - v;   // q - wc
                    Cb[rowoff + n] = f2b(d * d);
                } else if (EPI == EPI_WC_OUT) {
                    Cf[rowoff + n] = v;
                } else if (EPI == EPI_COMMON) {
                    Cb[rowoff + n] = f2b(v + bias[n]);
                } else if (EPI == EPI_TANH) {
                    Cb[rowoff + n] = f2b(tanhf(v + bias[n]));
                } else if (EPI == EPI_MATRIX) {
                    const float p = Prev ? Prev[rowoff + n] : 1.0f;
                    float mval = tanhf(v + bias[n]) + p;
                    mval = fminf(fmaxf(mval, -1.0f), 1.0f);
                    Cf[rowoff + n] = mval;                          // matrix state
                    Cb[rowoff + n] = f2b(Qf[rowoff + n] * mval);    // qeff bf16
                }
            }
        }
    }
}

// ---------------------------------------------------------------------------
// fp32 -> bf16 straight cast (grid-stride, 4 elems/thread)
__global__ void castf2b_kernel(const float* __restrict__ src, u16* __restrict__ dst, int n4)
{
    int i = blockIdx.x * blockDim.x + threadIdx.x;
    const int stride = gridDim.x * blockDim.x;
    for (; i < n4; i += stride) {
        const float4 v = ((const float4*)src)[i];
        ushort4 o;
        o.x = f2b(v.x); o.y = f2b(v.y); o.z = f2b(v.z); o.w = f2b(v.w);
        ((ushort4*)dst)[i] = o;
    }
}

// cast + transpose: src fp32 [R][Cn] (batched via blockIdx.z) -> dstT bf16 [Cn][R]
// and optionally dstS bf16 [R][Cn].
__global__ __launch_bounds__(256)
void transpose_cast_kernel(const float* __restrict__ src, u16* __restrict__ dstT,
                           u16* __restrict__ dstS, int R, int Cn)
{
    const size_t boff = (size_t)blockIdx.z * R * Cn;
    src += boff; dstT += boff;
    if (dstS) dstS += boff;

    __shared__ u16 T[64][68];   // 68: keeps 8B alignment, spreads banks
    const int r0 = blockIdx.y * 64, c0 = blockIdx.x * 64;
    const int t = threadIdx.x;
    const int rl = t >> 2, cb = (t & 3) * 16;

    #pragma unroll
    for (int j = 0; j < 4; ++j) {
        const float4 v = *(const float4*)(src + (size_t)(r0 + rl) * Cn + c0 + cb + 4 * j);
        ushort4 o;
        o.x = f2b(v.x); o.y = f2b(v.y); o.z = f2b(v.z); o.w = f2b(v.w);
        *(ushort4*)&T[rl][cb + 4 * j] = o;
        if (dstS) *(ushort4*)(dstS + (size_t)(r0 + rl) * Cn + c0 + cb + 4 * j) = o;
    }
    __syncthreads();
    const int cl = t >> 2, rb = (t & 3) * 16;
    #pragma unroll
    for (int j = 0; j < 4; ++j) {
        ushort4 o;
        o.x = T[rb + 4 * j + 0][cl];
        o.y = T[rb + 4 * j + 1][cl];
        o.z = T[rb + 4 * j + 2][cl];
        o.w = T[rb + 4 * j + 3][cl];
        *(ushort4*)(dstT + (size_t)(c0 + cl) * R + r0 + rb + 4 * j) = o;
    }
}

// cn[b][c] = 1/(||S[b][:,c]||_2 + 1e-8); S is [b][q][c], reduce over q.
// One block per b; thread t owns c = t&127; fully coalesced (linear = 256i + t).
__global__ __launch_bounds__(256)
void cnorm2_kernel(const float* __restrict__ S, float* __restrict__ cn)
{
    const int b = blockIdx.x;
    const float* Sb = S + (size_t)b * NQ_ * NC_;
    const int t = threadIdx.x;
    float s = 0.f;
    #pragma unroll 4
    for (int i = 0; i < (NQ_ * NC_) / 256; ++i) {
        const float v = Sb[i * 256 + t];
        s += v * v;
    }
    __shared__ float red[256];
    red[t] = s;
    __syncthreads();
    if (t < 128) {
        const float tot = red[t] + red[t + 128];
        cn[b * NC_ + t] = 1.0f / (sqrtf(tot) + 1e-8f);
    }
}

// softmax over c (fast axis of S[b][q][c]); wave per (b,q).
// writes fp32 attn (out) and bf16 attn (ws) rows.
__global__ __launch_bounds__(256)
void softmax2_kernel(const float* __restrict__ S, const float* __restrict__ cn,
                     const float* __restrict__ smooth,
                     float* __restrict__ attn, u16* __restrict__ attnbf)
{
    const int wi = (blockIdx.x * blockDim.x + threadIdx.x) >> 6;   // b*NQ + q
    const int l = threadIdx.x & 63;
    const int b = wi >> 8;
    const float sm = smooth ? smooth[wi] : 10.0f;
    const float2 sv = *(const float2*)(S + (size_t)wi * NC_ + 2 * l);
    const float2 cv = *(const float2*)(cn + b * NC_ + 2 * l);
    float v0 = sv.x * cv.x * sm;
    float v1 = sv.y * cv.y * sm;
    float m = fmaxf(v0, v1);
    #pragma unroll
    for (int off = 32; off; off >>= 1) m = fmaxf(m, __shfl_xor(m, off, 64));
    float e0 = expf(v0 - m), e1 = expf(v1 - m);
    float s = e0 + e1;
    #pragma unroll
    for (int off = 32; off; off >>= 1) s += __shfl_xor(s, off, 64);
    const float inv = 1.0f / s;
    e0 *= inv; e1 *= inv;
    float2 o; o.x = e0; o.y = e1;
    *(float2*)(attn + (size_t)wi * NC_ + 2 * l) = o;
    ushort2 ob; ob.x = f2b(e0); ob.y = f2b(e1);
    *(ushort2*)(attnbf + (size_t)wi * NC_ + 2 * l) = ob;
}

// in-place l2norm of bf16 rows of length 256; wave per row.
__global__ __launch_bounds__(256)
void rownorm_bf_kernel(u16* __restrict__ X)
{
    const int wi = (blockIdx.x * blockDim.x + threadIdx.x) >> 6;
    const int l = threadIdx.x & 63;
    u16* row = X + (size_t)wi * AD_ + 4 * l;
    const ushort4 raw = *(const ushort4*)row;
    float f0 = b2f(raw.x), f1 = b2f(raw.y), f2 = b2f(raw.z), f3 = b2f(raw.w);
    float s = f0 * f0 + f1 * f1 + f2 * f2 + f3 * f3;
    #pragma unroll
    for (int off = 32; off; off >>= 1) s += __shfl_xor(s, off, 64);
    const float inv = 1.0f / (sqrtf(s) + 1e-8f);
    ushort4 o;
    o.x = f2b(f0 * inv); o.y = f2b(f1 * inv); o.z = f2b(f2 * inv); o.w = f2b(f3 * inv);
    *(ushort4*)row = o;
}

// smooth = relu(h2 . sw_W2 + sw_b2 + smooth_prev); wave per (b,q); h2 bf16.
__global__ __launch_bounds__(256)
void smooth_kernel(const u16* __restrict__ h2, const float* __restrict__ W2,
                   const float* __restrict__ b2, float* __restrict__ smooth, int first)
{
    const int wi = (blockIdx.x * blockDim.x + threadIdx.x) >> 6;
    const int l = threadIdx.x & 63;
    const u16* r = h2 + (size_t)wi * SH_;
    float s = b2f(r[l]) * W2[l] + b2f(r[l + 64]) * W2[l + 64];
    #pragma unroll
    for (int off = 32; off; off >>= 1) s += __shfl_xor(s, off, 64);
    if (l == 0) {
        const float sp = first ? 10.0f : smooth[wi];
        smooth[wi] = fmaxf(s + b2[0] + sp, 0.0f);
    }
}

__global__ void copy4_kernel(const float4* __restrict__ src, float4* __restrict__ dst, int n)
{
    int i = blockIdx.x * blockDim.x + threadIdx.x;
    const int stride = gridDim.x * blockDim.x;
    for (; i < n; i += stride) dst[i] = src[i];
}

// ---------------------------------------------------------------------------
extern "C" void kernel_launch(void* const* d_in, const int* in_sizes, int n_in,
                              void* d_out, int out_size, void* d_ws, size_t ws_size,
                              hipStream_t stream)
{
    (void)in_sizes; (void)n_in; (void)out_size; (void)ws_size;

    const float* query   = (const float*)d_in[0];
    const float* context = (const float*)d_in[1];
    const float* cw_W    = (const float*)d_in[2];
    const float* cw_b    = (const float*)d_in[3];
    const float* sw_W1   = (const float*)d_in[4];
    const float* sw_b1   = (const float*)d_in[5];
    const float* sw_W2   = (const float*)d_in[6];
    const float* sw_b2   = (const float*)d_in[7];
    const float* mw_W1   = (const float*)d_in[8];
    const float* mw_b1   = (const float*)d_in[9];
    const float* mw_W2   = (const float*)d_in[10];
    const float* mw_b2   = (const float*)d_in[11];

    const size_t QD  = (size_t)B_ * NQ_ * D_;    // 33.55M
    const size_t CD  = (size_t)B_ * NC_ * D_;    // 16.78M
    const size_t QC  = (size_t)B_ * NQ_ * NC_;   // 4.19M
    const size_t QAD = (size_t)B_ * NQ_ * AD_;   // 8.39M
    const size_t QMH = (size_t)B_ * NQ_ * MH_;   // 16.78M

    float* out      = (float*)d_out;
    float* out_q    = out;              // final: query copy; interim: matrix fp32 state
    float* out_wc   = out + QD;         // final: wc fp32; interim: [qeff bf16 | sqd bf16]
    float* out_attn = out_wc + QD;      // final: attn fp32; interim: h2bf (first 8.4MB)

    float* matrix = out_q;
    u16*   qeff   = (u16*)out_wc;
    u16*   sqd    = (u16*)out_wc + QD;
    u16*   h2bf   = (u16*)out_attn;

    // workspace (~147 MB)
    char* p = (char*)d_ws;
    u16* ctxbf    = (u16*)p;  p += CD * 2;
    u16* ctxT     = (u16*)p;  p += CD * 2;
    u16* cwT      = (u16*)p;  p += (size_t)2 * D_ * AD_ * 2;
    u16* mw1T     = (u16*)p;  p += (size_t)2 * AD_ * MH_ * 2;
    u16* mw2T     = (u16*)p;  p += (size_t)2 * MH_ * D_ * 2;
    u16* sw1T     = (u16*)p;  p += (size_t)2 * AD_ * SH_ * 2;
    float* S      = (float*)p; p += QC * 4;
    u16* commonbf = (u16*)p;  p += QAD * 2;
    u16* attnbf   = (u16*)p;  p += QC * 2;
    u16* hbf      = (u16*)p;  p += QMH * 2;
    float* smooth = (float*)p; p += (size_t)B_ * NQ_ * 4;
    float* cn     = (float*)p; p += (size_t)B_ * NC_ * 4;

    const dim3 blk(256);

    // ---- prep: cast query -> qeff (scan0's A, matrix==1), ctx both layouts, weights ----
    castf2b_kernel<<<2048, blk, 0, stream>>>(query, qeff, (int)(QD / 4));
    transpose_cast_kernel<<<dim3(D_ / 64, NC_ / 64, B_), blk, 0, stream>>>(
        context, ctxT, ctxbf, NC_, D_);
    for (int i = 0; i < 2; ++i) {
        transpose_cast_kernel<<<dim3(AD_ / 64, D_ / 64, 1), blk, 0, stream>>>(
            cw_W + (size_t)i * D_ * AD_, cwT + (size_t)i * D_ * AD_, nullptr, D_, AD_);
        transpose_cast_kernel<<<dim3(MH_ / 64, AD_ / 64, 1), blk, 0, stream>>>(
            mw_W1 + (size_t)i * AD_ * MH_, mw1T + (size_t)i * AD_ * MH_, nullptr, AD_, MH_);
        transpose_cast_kernel<<<dim3(D_ / 64, MH_ / 64, 1), blk, 0, stream>>>(
            mw_W2 + (size_t)i * MH_ * D_, mw2T + (size_t)i * MH_ * D_, nullptr, MH_, D_);
        transpose_cast_kernel<<<dim3(SH_ / 64, AD_ / 64, 1), blk, 0, stream>>>(
            sw_W1 + (size_t)i * AD_ * SH_, sw1T + (size_t)i * AD_ * SH_, nullptr, AD_, SH_);
    }

    // ---- scan: S[q][c] = leaky(qeff . ctx^T); colnorm; softmax; wc-consumer ----
    auto scan = [&](const float* smo, int last) {
        mm_bt<EPI_SCORES><<<dim3(NC_ / 128, NQ_ / 128, B_), blk, 0, stream>>>(
            qeff, (long)(NQ_ * D_), ctxbf, (long)(NC_ * D_), nullptr,
            S, nullptr, nullptr, nullptr, NQ_, NC_, D_);
        cnorm2_kernel<<<B_, blk, 0, stream>>>(S, cn);
        softmax2_kernel<<<(B_ * NQ_) / 4, blk, 0, stream>>>(S, cn, smo, out_attn, attnbf);
        if (!last)   // sqd = bf16((q - attn@ctx)^2)
            mm_bt<EPI_WC_SQD><<<dim3(D_ / 128, NQ_ / 128, B_), blk, 0, stream>>>(
                attnbf, (long)(NQ_ * NC_), ctxT, (long)(D_ * NC_), nullptr,
                nullptr, sqd, query, nullptr, NQ_, D_, NC_);
        else         // final wc fp32
            mm_bt<EPI_WC_OUT><<<dim3(D_ / 128, NQ_ / 128, B_), blk, 0, stream>>>(
                attnbf, (long)(NQ_ * NC_), ctxT, (long)(D_ * NC_), nullptr,
                out_wc, nullptr, nullptr, nullptr, NQ_, D_, NC_);
    };

    auto layer = [&](int i) {
        // common = l2norm(sqd @ cw_W + cw_b)  (bf16)
        mm_bt<EPI_COMMON><<<dim3(AD_ / 128, NQ_ / 128, B_), blk, 0, stream>>>(
            sqd, (long)(NQ_ * D_), cwT + (size_t)i * D_ * AD_, 0L, cw_b + (size_t)i * AD_,
            nullptr, commonbf, nullptr, nullptr, NQ_, AD_, D_);
        rownorm_bf_kernel<<<(B_ * NQ_) / 4, blk, 0, stream>>>(commonbf);
        // h = tanh(common @ mw_W1 + b1)  (bf16)
        mm_bt<EPI_TANH><<<dim3(MH_ / 128, NQ_ / 128, B_), blk, 0, stream>>>(
            commonbf, (long)(NQ_ * AD_), mw1T + (size_t)i * AD_ * MH_, 0L,
            mw_b1 + (size_t)i * MH_, nullptr, hbf, nullptr, nullptr, NQ_, MH_, AD_);
        // matrix = clip(tanh(h @ mw_W2 + b2) + prev, -1, 1); qeff = bf16(q * matrix)
        mm_bt<EPI_MATRIX><<<dim3(D_ / 128, NQ_ / 128, B_), blk, 0, stream>>>(
            hbf, (long)(NQ_ * MH_), mw2T + (size_t)i * MH_ * D_, 0L,
            mw_b2 + (size_t)i * D_, matrix, qeff, query,
            (i == 0 ? nullptr : matrix), NQ_, D_, MH_);
        // h2 = tanh(common @ sw_W1 + b1)  (bf16)
        mm_bt<EPI_TANH><<<dim3(SH_ / 128, NQ_ / 128, B_), blk, 0, stream>>>(
            commonbf, (long)(NQ_ * AD_), sw1T + (size_t)i * AD_ * SH_, 0L,
            sw_b1 + (size_t)i * SH_, nullptr, h2bf, nullptr, nullptr, NQ_, SH_, AD_);
        smooth_kernel<<<(B_ * NQ_) / 4, blk, 0, stream>>>(
            h2bf, sw_W2 + (size_t)i * SH_, sw_b2 + i, smooth, (i == 0) ? 1 : 0);
    };

    scan(nullptr, 0);   // matrix = 1, smooth = 10
    layer(0);
    scan(smooth, 0);
    layer(1);
    scan(smooth, 1);    // final wc -> out_wc, attn -> out_attn

    copy4_kernel<<<4096, blk, 0, stream>>>(
        (const float4*)query, (float4*)out_q, (int)(QD / 4));
}